// Round 12
// baseline (206.024 us; speedup 1.0000x reference)
//
#include <hip/hip_runtime.h>

#define BATCH 8192

typedef __fp16 h2 __attribute__((ext_vector_type(2)));
typedef __fp16 h8 __attribute__((ext_vector_type(8)));
typedef float f32x4 __attribute__((ext_vector_type(4)));
union H2U { unsigned u; h2 h; };
union U4H8 { uint4 u; h8 h; };

// ---------------------------------------------------------------------------
// Kernel 0: prep — pack conv2 weights as fp16 W[16 oc][96 k], k = tap*8+ic,
// zero-padded k>=72. Stored as 768 dwords (fp16 pairs, ic even/odd).
// ---------------------------------------------------------------------------
__global__ __launch_bounds__(256) void prep(const float* __restrict__ c2w,
                                            unsigned* __restrict__ w2h) {
    int i = blockIdx.x * 256 + threadIdx.x;
    if (i < 768) {
        int oc = i / 48, kp = i - oc * 48;
        int k0 = 2 * kp;
        int tap = k0 >> 3, ic0 = k0 & 7;
        float lo = 0.f, hi = 0.f;
        if (tap < 9) {
            lo = c2w[oc * 72 + ic0 * 9 + tap];
            hi = c2w[oc * 72 + (ic0 + 1) * 9 + tap];
        }
        H2U u; u.h = __builtin_amdgcn_cvt_pkrtz(lo, hi);
        w2h[i] = u.u;
    }
}

// ---------------------------------------------------------------------------
// Kernel 1: fused conv1+pool -> im2col -> MFMA conv2 -> pool -> v-dot -> tail.
// One block = one sample, 256 threads (4 waves).
// conv2 as GEMM: D^T[196pos][16oc] = P[196][72] x W^T[72][16] via
// mfma_f32_16x16x32_f16, 13 pos-tiles x 3 K-steps. A/B fragments both load
// 8-contiguous-k blocks => correct under any (lane-group,reg)->k mapping
// (k-permutation invariance; only C/D mapping col=lane&15,row=4*(l>>4)+r and
// A-row/B-col = lane&15 are assumed, per m89-verified layout).
// LDS (floats, lifetime-overlapped), 11856 f = 47.4 KB => 3 blocks/CU:
//   [0,10816)      P fp16[208 pos][104] (52 dw rows, 16B-aligned, k pad 0)
//                  ∪ xs[900] (phases 0-1)  ∪ c2out[196][17] f32 (phases 4-5)
//   [10816,11840)  p1h uint[256 pos][4] (conv1 out, fp16-packed, phases 0-2)
//                  ∪ p2[784] (phases 5+)
//   [11840,11856)  vred
// ---------------------------------------------------------------------------
__global__ __launch_bounds__(256, 4) void fused_fwd(
    const float* __restrict__ x,        // [B,1,28,28]
    const float* __restrict__ params,   // [B,4]
    const float* __restrict__ c1w,      // [8,1,3,3]
    const float* __restrict__ c1b,      // [8]
    const float* __restrict__ c2b,      // [16]
    const float* __restrict__ qkvw,     // [12,784]
    const float* __restrict__ qkvb,     // [12]
    const float* __restrict__ outw,     // [4,4]
    const float* __restrict__ outb,     // [4]
    const unsigned* __restrict__ w2h,   // [16][48] fp16-pair conv2 weights
    float* __restrict__ pre)            // ws: [B,4] pre-BN
{
    __shared__ __align__(16) float lds[11856];
    float*    xs   = lds;                        // [900]
    unsigned* Pu   = (unsigned*)lds;             // [208][52]
    float*    c2o  = lds;                        // [196][17]
    unsigned* p1h  = (unsigned*)(lds + 10816);   // [256][4]
    float*    p2   = lds + 10816;                // [784]
    float*    vred = lds + 11840;                // [16]

    const int tid = threadIdx.x;
    const int b = blockIdx.x;
    const int lane = tid & 63;
    const int lane15 = lane & 15;     // A-row / B-col / D-col (oc)
    const int g = lane >> 4;          // k-group

    // ---- B-fragments + bias: issued early, hidden under phases 0-2 ----
    U4H8 bf0, bf1, bf2;
    bf0.u = ((const uint4*)w2h)[lane15 * 12 + 0 + g];
    bf1.u = ((const uint4*)w2h)[lane15 * 12 + 4 + g];
    bf2.u = ((const uint4*)w2h)[lane15 * 12 + 8 + g];
    const float bias16 = c2b[lane15];

    // ---- phase 0: stage input (zero-padded 30x30) + zero p1h ----
    for (int i = tid; i < 900; i += 256) {
        int h = i / 30, w = i - h * 30;
        float v = 0.f;
        if (h >= 1 && h <= 28 && w >= 1 && w <= 28)
            v = x[b * 784 + (h - 1) * 28 + (w - 1)];
        xs[i] = v;
    }
    ((uint4*)p1h)[tid] = make_uint4(0u, 0u, 0u, 0u);
    __syncthreads();

    // ---- phase 1: conv1 (1->8) + relu + maxpool2 -> p1h fp16x8 ----
    {
        const int pos = tid < 196 ? tid : 195;   // clamp: uniform control flow
        const int ph = pos / 14, pw = pos - ph * 14;
        const float* base = &xs[(2 * ph) * 30 + 2 * pw];
        float in[4][4];
        #pragma unroll
        for (int r = 0; r < 4; ++r)
            #pragma unroll
            for (int c = 0; c < 4; ++c)
                in[r][c] = base[r * 30 + c];
        float o[8];
        #pragma unroll
        for (int oc = 0; oc < 8; ++oc) {
            float m = 0.f;   // max(relu) == relu(max); relu floor is 0
            #pragma unroll
            for (int dh = 0; dh < 2; ++dh)
                #pragma unroll
                for (int dw = 0; dw < 2; ++dw) {
                    float a = c1b[oc];
                    #pragma unroll
                    for (int r = 0; r < 3; ++r)
                        #pragma unroll
                        for (int c = 0; c < 3; ++c)
                            a += in[dh + r][dw + c] * c1w[oc * 9 + r * 3 + c];
                    m = fmaxf(m, a);
                }
            o[oc] = m;
        }
        if (tid < 196) {
            H2U u0, u1, u2, u3;
            u0.h = __builtin_amdgcn_cvt_pkrtz(o[0], o[1]);
            u1.h = __builtin_amdgcn_cvt_pkrtz(o[2], o[3]);
            u2.h = __builtin_amdgcn_cvt_pkrtz(o[4], o[5]);
            u3.h = __builtin_amdgcn_cvt_pkrtz(o[6], o[7]);
            ((uint4*)p1h)[(ph + 1) * 16 + (pw + 1)] =
                make_uint4(u0.u, u1.u, u2.u, u3.u);
        }
    }
    __syncthreads();   // xs dead after here; P may overwrite

    // ---- phase 2: im2col P[pos][k=tap*8+ic] fp16 + zero-pad rows/K ----
    {
        const uint4 z4 = make_uint4(0u, 0u, 0u, 0u);
        if (tid < 196) {
            const int h = tid / 14, w = tid - 14 * (tid / 14);
            uint4* dst = (uint4*)(Pu + tid * 52);
            #pragma unroll
            for (int t = 0; t < 9; ++t) {
                const int dh = t / 3, dw = t - 3 * (t / 3);
                dst[t] = ((const uint4*)p1h)[(h + dh) * 16 + (w + dw)];
            }
            dst[9] = z4; dst[10] = z4; dst[11] = z4;   // k 72..95 = 0
        } else if (tid < 208) {
            uint4* dst = (uint4*)(Pu + tid * 52);
            #pragma unroll
            for (int t = 0; t < 12; ++t) dst[t] = z4;  // pad rows 196..207
        }
    }
    __syncthreads();

    // ---- phase 3: MFMA — wave wv owns tiles 4wv..4wv+3 (valid < 13) ----
    const int wv = tid >> 6;
    f32x4 acc[4];
    #pragma unroll
    for (int t = 0; t < 4; ++t) acc[t] = (f32x4){0.f, 0.f, 0.f, 0.f};
    #pragma unroll
    for (int t = 0; t < 4; ++t) {
        const int tile = wv * 4 + t;
        if (tile < 13) {
            const char* abase = (const char*)Pu
                              + (tile * 16 + lane15) * 208 + g * 16;
            U4H8 a0, a1, a2;
            a0.u = *(const uint4*)(abase);
            a1.u = *(const uint4*)(abase + 64);
            a2.u = *(const uint4*)(abase + 128);
            acc[t] = __builtin_amdgcn_mfma_f32_16x16x32_f16(a0.h, bf0.h, acc[t], 0, 0, 0);
            acc[t] = __builtin_amdgcn_mfma_f32_16x16x32_f16(a1.h, bf1.h, acc[t], 0, 0, 0);
            acc[t] = __builtin_amdgcn_mfma_f32_16x16x32_f16(a2.h, bf2.h, acc[t], 0, 0, 0);
        }
    }
    __syncthreads();   // all P reads complete before c2o overwrites it

    // ---- phase 4: write c2out[pos][oc] (stride 17) = relu(D + bias) ----
    #pragma unroll
    for (int t = 0; t < 4; ++t) {
        const int tile = wv * 4 + t;
        if (tile < 13) {
            #pragma unroll
            for (int r = 0; r < 4; ++r) {
                const int pos = tile * 16 + g * 4 + r;   // C/D row
                if (pos < 196)
                    c2o[pos * 17 + lane15] = fmaxf(acc[t][r] + bias16, 0.f);
            }
        }
    }
    __syncthreads();

    // ---- phase 5: maxpool2 -> p2 [16 oc][7][7] ----
    for (int it = tid; it < 784; it += 256) {
        int oc = it / 49, r = it - oc * 49;
        int ph = r / 7, pw = r - 7 * (r / 7);
        int pos0 = (2 * ph) * 14 + 2 * pw;
        float m = fmaxf(fmaxf(c2o[pos0 * 17 + oc], c2o[(pos0 + 1) * 17 + oc]),
                        fmaxf(c2o[(pos0 + 14) * 17 + oc], c2o[(pos0 + 15) * 17 + oc]));
        p2[it] = m;
    }
    __syncthreads();

    // ---- phase 6: v = p2 . qkv_w[8..11] (q,k provably unused), float4 ----
    float v0 = 0.f, v1 = 0.f, v2 = 0.f, v3 = 0.f;
    if (tid < 196) {
        float4 f  = *(const float4*)&p2[tid * 4];
        float4 a0 = ((const float4*)&qkvw[8 * 784])[tid];
        float4 a1 = ((const float4*)&qkvw[9 * 784])[tid];
        float4 a2 = ((const float4*)&qkvw[10 * 784])[tid];
        float4 a3 = ((const float4*)&qkvw[11 * 784])[tid];
        v0 = f.x * a0.x + f.y * a0.y + f.z * a0.z + f.w * a0.w;
        v1 = f.x * a1.x + f.y * a1.y + f.z * a1.z + f.w * a1.w;
        v2 = f.x * a2.x + f.y * a2.y + f.z * a2.z + f.w * a2.w;
        v3 = f.x * a3.x + f.y * a3.y + f.z * a3.z + f.w * a3.w;
    }
    #pragma unroll
    for (int off = 32; off > 0; off >>= 1) {
        v0 += __shfl_xor(v0, off);
        v1 += __shfl_xor(v1, off);
        v2 += __shfl_xor(v2, off);
        v3 += __shfl_xor(v3, off);
    }
    if ((tid & 63) == 0) {
        vred[wv * 4 + 0] = v0; vred[wv * 4 + 1] = v1;
        vred[wv * 4 + 2] = v2; vred[wv * 4 + 3] = v3;
    }
    __syncthreads();

    // ---- tail: 4 lanes, one output channel each ----
    if (tid < 4) {
        float vv[4];
        #pragma unroll
        for (int j = 0; j < 4; ++j)
            vv[j] = vred[0 + j] + vred[4 + j] + vred[8 + j] + vred[12 + j]
                  + qkvb[8 + j];

        float lg[4];
        float run = 1.f;
        #pragma unroll
        for (int j = 0; j < 4; ++j) { run *= cosf(params[b * 4 + j]); lg[j] = run; }
        float mx = fmaxf(fmaxf(lg[0], lg[1]), fmaxf(lg[2], lg[3]));
        float e[4], s = 0.f;
        #pragma unroll
        for (int j = 0; j < 4; ++j) { e[j] = expf(lg[j] - mx); s += e[j]; }
        float inv = 1.f / s;

        float t = outb[tid];
        #pragma unroll
        for (int j = 0; j < 4; ++j) t += outw[tid * 4 + j] * (e[j] * inv * vv[j]);
        pre[b * 4 + tid] = t;
    }
}

// ---------------------------------------------------------------------------
// Kernel 2: BN stats + apply. 128 blocks x 256 threads; each block
// redundantly reduces L2-resident pre[8192x4] then applies to its 64 samples.
// ---------------------------------------------------------------------------
__global__ __launch_bounds__(256) void bn_final(
    const float* __restrict__ pre, const float* __restrict__ gamma,
    const float* __restrict__ beta, float* __restrict__ out)
{
    __shared__ float red[4][8];
    const int tid = threadIdx.x;
    const float4* pre4 = (const float4*)pre;

    float4 s = make_float4(0.f, 0.f, 0.f, 0.f);
    float4 q = make_float4(0.f, 0.f, 0.f, 0.f);
    for (int i = tid; i < 8192; i += 256) {
        float4 v = pre4[i];
        s.x += v.x; s.y += v.y; s.z += v.z; s.w += v.w;
        q.x += v.x * v.x; q.y += v.y * v.y; q.z += v.z * v.z; q.w += v.w * v.w;
    }
    #pragma unroll
    for (int off = 32; off > 0; off >>= 1) {
        s.x += __shfl_xor(s.x, off); s.y += __shfl_xor(s.y, off);
        s.z += __shfl_xor(s.z, off); s.w += __shfl_xor(s.w, off);
        q.x += __shfl_xor(q.x, off); q.y += __shfl_xor(q.y, off);
        q.z += __shfl_xor(q.z, off); q.w += __shfl_xor(q.w, off);
    }
    if ((tid & 63) == 0) {
        const int wv = tid >> 6;
        red[wv][0] = s.x; red[wv][1] = s.y; red[wv][2] = s.z; red[wv][3] = s.w;
        red[wv][4] = q.x; red[wv][5] = q.y; red[wv][6] = q.z; red[wv][7] = q.w;
    }
    __syncthreads();

    float mu[4], inv[4];
    #pragma unroll
    for (int c = 0; c < 4; ++c) {
        float ts = red[0][c] + red[1][c] + red[2][c] + red[3][c];
        float tq = red[0][4 + c] + red[1][4 + c] + red[2][4 + c] + red[3][4 + c];
        float m = ts * (1.f / 8192.f);
        mu[c] = m;
        inv[c] = rsqrtf(tq * (1.f / 8192.f) - m * m + 1e-5f);
    }

    if (tid < 64) {
        const int i = blockIdx.x * 64 + tid;
        float4 v = pre4[i];
        float4 gm = *(const float4*)gamma;
        float4 be = *(const float4*)beta;
        float4 o;
        o.x = (v.x - mu[0]) * inv[0] * gm.x + be.x;
        o.y = (v.y - mu[1]) * inv[1] * gm.y + be.y;
        o.z = (v.z - mu[2]) * inv[2] * gm.z + be.z;
        o.w = (v.w - mu[3]) * inv[3] * gm.w + be.w;
        ((float4*)out)[i] = o;
    }
}

extern "C" void kernel_launch(void* const* d_in, const int* in_sizes, int n_in,
                              void* d_out, int out_size, void* d_ws, size_t ws_size,
                              hipStream_t stream) {
    const float* x      = (const float*)d_in[0];
    const float* params = (const float*)d_in[1];
    const float* c1w    = (const float*)d_in[2];
    const float* c1b    = (const float*)d_in[3];
    const float* c2w    = (const float*)d_in[4];
    const float* c2b    = (const float*)d_in[5];
    const float* qkvw   = (const float*)d_in[6];
    const float* qkvb   = (const float*)d_in[7];
    const float* outw   = (const float*)d_in[8];
    const float* outb   = (const float*)d_in[9];
    const float* gamma  = (const float*)d_in[10];
    const float* beta   = (const float*)d_in[11];

    unsigned* w2h = (unsigned*)d_ws;            // 768 uints
    float*    pre = (float*)d_ws + 1024;        // 32768 floats (16B-aligned)

    prep<<<3, 256, 0, stream>>>(c2w, w2h);
    fused_fwd<<<BATCH, 256, 0, stream>>>(x, params, c1w, c1b, c2b,
                                         qkvw, qkvb, outw, outb, w2h, pre);
    bn_final<<<128, 256, 0, stream>>>(pre, gamma, beta, (float*)d_out);
}

// Round 13
// 149.137 us; speedup vs baseline: 1.3814x; 1.3814x over previous
//
#include <hip/hip_runtime.h>

#define BATCH 8192

typedef __fp16 h2 __attribute__((ext_vector_type(2)));
typedef __fp16 h8 __attribute__((ext_vector_type(8)));
typedef float f32x4 __attribute__((ext_vector_type(4)));
union H2U { unsigned u; h2 h; };
union U4H8 { uint4 u; h8 h; };

// ---------------------------------------------------------------------------
// Kernel 0: prep — pack conv2 weights as fp16 W[16 oc][96 k], k = tap*8+ic,
// zero-padded k>=72. Stored as 768 dwords (fp16 pairs, ic even/odd).
// ---------------------------------------------------------------------------
__global__ __launch_bounds__(256) void prep(const float* __restrict__ c2w,
                                            unsigned* __restrict__ w2h) {
    int i = blockIdx.x * 256 + threadIdx.x;
    if (i < 768) {
        int oc = i / 48, kp = i - oc * 48;
        int k0 = 2 * kp;
        int tap = k0 >> 3, ic0 = k0 & 7;
        float lo = 0.f, hi = 0.f;
        if (tap < 9) {
            lo = c2w[oc * 72 + ic0 * 9 + tap];
            hi = c2w[oc * 72 + (ic0 + 1) * 9 + tap];
        }
        H2U u; u.h = __builtin_amdgcn_cvt_pkrtz(lo, hi);
        w2h[i] = u.u;
    }
}

// ---------------------------------------------------------------------------
// Kernel 1: fused conv1+pool -> MFMA conv2 (zero-copy im2col) -> pool -> v -> tail.
// One block = one sample, 256 threads (4 waves).
// conv2 GEMM D^T[196pos][16oc] = P[196][72] x W^T[72][16], 16x16x32 f16 MFMA,
// 13 pos-tiles x 3 K-steps. A-fragment (ks,g) = k 32ks+8g..+7 = ONE tap's
// uint4 in p1h => read directly, no im2col staging (round-12 lesson: 43KB P
// matrix -> 3 blocks/CU -> latency-bound). B zero-padded k>=72; A-tap clamped
// to 8 so pad contributions are B=0 * finite = 0. Pos>=196 rows clamped to
// 195, D rows >=196 discarded.
// LDS (floats, lifetime-overlapped), 4372 f = 17.5 KB => 8 blocks/CU:
//   [0,3332)    xs[900] (phases 0-1) ∪ c2o[196][17] f32 (phases 3-4)
//   [3332,4356) p1h uint[256][4] (fp16 conv1 out, phases 1-3) ∪ p2[784] (4-5)
//   [4356,4372) vred
// ---------------------------------------------------------------------------
__global__ __launch_bounds__(256, 4) void fused_fwd(
    const float* __restrict__ x,        // [B,1,28,28]
    const float* __restrict__ params,   // [B,4]
    const float* __restrict__ c1w,      // [8,1,3,3]
    const float* __restrict__ c1b,      // [8]
    const float* __restrict__ c2b,      // [16]
    const float* __restrict__ qkvw,     // [12,784]
    const float* __restrict__ qkvb,     // [12]
    const float* __restrict__ outw,     // [4,4]
    const float* __restrict__ outb,     // [4]
    const unsigned* __restrict__ w2h,   // [16][48] fp16-pair conv2 weights
    float* __restrict__ pre)            // ws: [B,4] pre-BN
{
    __shared__ __align__(16) float lds[4372];
    float*    xs   = lds;                        // [900]
    float*    c2o  = lds;                        // [196][17]
    unsigned* p1h  = (unsigned*)(lds + 3332);    // [256][4] dwords
    float*    p2   = lds + 3332;                 // [784]
    float*    vred = lds + 4356;                 // [16]

    const int tid = threadIdx.x;
    const int b = blockIdx.x;
    const int lane = tid & 63;
    const int lane15 = lane & 15;     // A-row(pos) / B-col(oc) / D-col(oc)
    const int g = lane >> 4;          // k-group

    // ---- B-fragments + bias: issued early, hidden under phases 0-1 ----
    U4H8 bf0, bf1, bf2;
    bf0.u = ((const uint4*)w2h)[lane15 * 12 + 0 + g];
    bf1.u = ((const uint4*)w2h)[lane15 * 12 + 4 + g];
    bf2.u = ((const uint4*)w2h)[lane15 * 12 + 8 + g];
    const float bias16 = c2b[lane15];

    // per-lane tap offsets for the 3 K-steps (tap = 4*ks+g, clamped to 8)
    const int t0 = g,     dh0 = t0 / 3, dw0 = t0 - 3 * (t0 / 3);
    const int t1 = 4 + g, dh1 = t1 / 3, dw1 = t1 - 3 * (t1 / 3);
    // ks=2: tap = min(8+g,8) = 8 -> (2,2); g>0 lanes read valid tap8, B=0 there

    // ---- phase 0: stage input (zero-padded 30x30) + zero p1h ----
    for (int i = tid; i < 900; i += 256) {
        int h = i / 30, w = i - h * 30;
        float v = 0.f;
        if (h >= 1 && h <= 28 && w >= 1 && w <= 28)
            v = x[b * 784 + (h - 1) * 28 + (w - 1)];
        xs[i] = v;
    }
    ((uint4*)p1h)[tid] = make_uint4(0u, 0u, 0u, 0u);
    __syncthreads();

    // ---- phase 1: conv1 (1->8) + relu + maxpool2 -> p1h fp16x8 ----
    {
        const int pos = tid < 196 ? tid : 195;   // clamp: uniform control flow
        const int ph = pos / 14, pw = pos - ph * 14;
        const float* base = &xs[(2 * ph) * 30 + 2 * pw];
        float in[4][4];
        #pragma unroll
        for (int r = 0; r < 4; ++r)
            #pragma unroll
            for (int c = 0; c < 4; ++c)
                in[r][c] = base[r * 30 + c];
        float o[8];
        #pragma unroll
        for (int oc = 0; oc < 8; ++oc) {
            float m = 0.f;   // max(relu) == relu(max); relu floor is 0
            #pragma unroll
            for (int dh = 0; dh < 2; ++dh)
                #pragma unroll
                for (int dw = 0; dw < 2; ++dw) {
                    float a = c1b[oc];
                    #pragma unroll
                    for (int r = 0; r < 3; ++r)
                        #pragma unroll
                        for (int c = 0; c < 3; ++c)
                            a += in[dh + r][dw + c] * c1w[oc * 9 + r * 3 + c];
                    m = fmaxf(m, a);
                }
            o[oc] = m;
        }
        if (tid < 196) {
            H2U u0, u1, u2, u3;
            u0.h = __builtin_amdgcn_cvt_pkrtz(o[0], o[1]);
            u1.h = __builtin_amdgcn_cvt_pkrtz(o[2], o[3]);
            u2.h = __builtin_amdgcn_cvt_pkrtz(o[4], o[5]);
            u3.h = __builtin_amdgcn_cvt_pkrtz(o[6], o[7]);
            ((uint4*)p1h)[(ph + 1) * 16 + (pw + 1)] =
                make_uint4(u0.u, u1.u, u2.u, u3.u);
        }
    }
    __syncthreads();   // p1h complete; xs dead (c2o may overwrite)

    // ---- phase 2: MFMA — wave wv owns pos-tiles 4wv..4wv+3 (valid < 13),
    //      A-fragments gathered directly from p1h (zero-copy im2col) ----
    const int wv = tid >> 6;
    f32x4 acc[4];
    #pragma unroll
    for (int t = 0; t < 4; ++t) acc[t] = (f32x4){0.f, 0.f, 0.f, 0.f};
    const uint4* p1h4 = (const uint4*)p1h;
    #pragma unroll
    for (int t = 0; t < 4; ++t) {
        const int tile = wv * 4 + t;
        if (tile < 13) {
            int pos = tile * 16 + lane15;
            pos = pos < 196 ? pos : 195;          // dup rows, D discarded
            const int h = pos / 14, w = pos - 14 * (pos / 14);
            U4H8 a0, a1, a2;
            a0.u = p1h4[(h + dh0) * 16 + (w + dw0)];
            a1.u = p1h4[(h + dh1) * 16 + (w + dw1)];
            a2.u = p1h4[(h + 2) * 16 + (w + 2)];  // tap 8 (clamped)
            acc[t] = __builtin_amdgcn_mfma_f32_16x16x32_f16(a0.h, bf0.h, acc[t], 0, 0, 0);
            acc[t] = __builtin_amdgcn_mfma_f32_16x16x32_f16(a1.h, bf1.h, acc[t], 0, 0, 0);
            acc[t] = __builtin_amdgcn_mfma_f32_16x16x32_f16(a2.h, bf2.h, acc[t], 0, 0, 0);
        }
    }

    // ---- phase 3: write c2o[pos][oc] (stride 17) = relu(D + bias) ----
    // (c2o overlaps xs, dead since the post-phase-1 barrier; no p1h overlap)
    #pragma unroll
    for (int t = 0; t < 4; ++t) {
        const int tile = wv * 4 + t;
        if (tile < 13) {
            #pragma unroll
            for (int r = 0; r < 4; ++r) {
                const int pos = tile * 16 + g * 4 + r;   // C/D row
                if (pos < 196)
                    c2o[pos * 17 + lane15] = fmaxf(acc[t][r] + bias16, 0.f);
            }
        }
    }
    __syncthreads();   // c2o complete; p1h dead (p2 may overwrite)

    // ---- phase 4: maxpool2 -> p2 [16 oc][7][7] ----
    for (int it = tid; it < 784; it += 256) {
        int oc = it / 49, r = it - oc * 49;
        int ph = r / 7, pw = r - 7 * (r / 7);
        int pos0 = (2 * ph) * 14 + 2 * pw;
        float m = fmaxf(fmaxf(c2o[pos0 * 17 + oc], c2o[(pos0 + 1) * 17 + oc]),
                        fmaxf(c2o[(pos0 + 14) * 17 + oc], c2o[(pos0 + 15) * 17 + oc]));
        p2[it] = m;
    }
    __syncthreads();

    // ---- phase 5: v = p2 . qkv_w[8..11] (q,k provably unused), float4 ----
    float v0 = 0.f, v1 = 0.f, v2 = 0.f, v3 = 0.f;
    if (tid < 196) {
        float4 f  = *(const float4*)&p2[tid * 4];
        float4 a0 = ((const float4*)&qkvw[8 * 784])[tid];
        float4 a1 = ((const float4*)&qkvw[9 * 784])[tid];
        float4 a2 = ((const float4*)&qkvw[10 * 784])[tid];
        float4 a3 = ((const float4*)&qkvw[11 * 784])[tid];
        v0 = f.x * a0.x + f.y * a0.y + f.z * a0.z + f.w * a0.w;
        v1 = f.x * a1.x + f.y * a1.y + f.z * a1.z + f.w * a1.w;
        v2 = f.x * a2.x + f.y * a2.y + f.z * a2.z + f.w * a2.w;
        v3 = f.x * a3.x + f.y * a3.y + f.z * a3.z + f.w * a3.w;
    }
    #pragma unroll
    for (int off = 32; off > 0; off >>= 1) {
        v0 += __shfl_xor(v0, off);
        v1 += __shfl_xor(v1, off);
        v2 += __shfl_xor(v2, off);
        v3 += __shfl_xor(v3, off);
    }
    if ((tid & 63) == 0) {
        vred[wv * 4 + 0] = v0; vred[wv * 4 + 1] = v1;
        vred[wv * 4 + 2] = v2; vred[wv * 4 + 3] = v3;
    }
    __syncthreads();

    // ---- tail: 4 lanes, one output channel each ----
    if (tid < 4) {
        float vv[4];
        #pragma unroll
        for (int j = 0; j < 4; ++j)
            vv[j] = vred[0 + j] + vred[4 + j] + vred[8 + j] + vred[12 + j]
                  + qkvb[8 + j];

        float lg[4];
        float run = 1.f;
        #pragma unroll
        for (int j = 0; j < 4; ++j) { run *= cosf(params[b * 4 + j]); lg[j] = run; }
        float mx = fmaxf(fmaxf(lg[0], lg[1]), fmaxf(lg[2], lg[3]));
        float e[4], s = 0.f;
        #pragma unroll
        for (int j = 0; j < 4; ++j) { e[j] = expf(lg[j] - mx); s += e[j]; }
        float inv = 1.f / s;

        float t = outb[tid];
        #pragma unroll
        for (int j = 0; j < 4; ++j) t += outw[tid * 4 + j] * (e[j] * inv * vv[j]);
        pre[b * 4 + tid] = t;
    }
}

// ---------------------------------------------------------------------------
// Kernel 2: BN stats + apply. 128 blocks x 256 threads; each block
// redundantly reduces L2-resident pre[8192x4] then applies to its 64 samples.
// ---------------------------------------------------------------------------
__global__ __launch_bounds__(256) void bn_final(
    const float* __restrict__ pre, const float* __restrict__ gamma,
    const float* __restrict__ beta, float* __restrict__ out)
{
    __shared__ float red[4][8];
    const int tid = threadIdx.x;
    const float4* pre4 = (const float4*)pre;

    float4 s = make_float4(0.f, 0.f, 0.f, 0.f);
    float4 q = make_float4(0.f, 0.f, 0.f, 0.f);
    for (int i = tid; i < 8192; i += 256) {
        float4 v = pre4[i];
        s.x += v.x; s.y += v.y; s.z += v.z; s.w += v.w;
        q.x += v.x * v.x; q.y += v.y * v.y; q.z += v.z * v.z; q.w += v.w * v.w;
    }
    #pragma unroll
    for (int off = 32; off > 0; off >>= 1) {
        s.x += __shfl_xor(s.x, off); s.y += __shfl_xor(s.y, off);
        s.z += __shfl_xor(s.z, off); s.w += __shfl_xor(s.w, off);
        q.x += __shfl_xor(q.x, off); q.y += __shfl_xor(q.y, off);
        q.z += __shfl_xor(q.z, off); q.w += __shfl_xor(q.w, off);
    }
    if ((tid & 63) == 0) {
        const int wv = tid >> 6;
        red[wv][0] = s.x; red[wv][1] = s.y; red[wv][2] = s.z; red[wv][3] = s.w;
        red[wv][4] = q.x; red[wv][5] = q.y; red[wv][6] = q.z; red[wv][7] = q.w;
    }
    __syncthreads();

    float mu[4], inv[4];
    #pragma unroll
    for (int c = 0; c < 4; ++c) {
        float ts = red[0][c] + red[1][c] + red[2][c] + red[3][c];
        float tq = red[0][4 + c] + red[1][4 + c] + red[2][4 + c] + red[3][4 + c];
        float m = ts * (1.f / 8192.f);
        mu[c] = m;
        inv[c] = rsqrtf(tq * (1.f / 8192.f) - m * m + 1e-5f);
    }

    if (tid < 64) {
        const int i = blockIdx.x * 64 + tid;
        float4 v = pre4[i];
        float4 gm = *(const float4*)gamma;
        float4 be = *(const float4*)beta;
        float4 o;
        o.x = (v.x - mu[0]) * inv[0] * gm.x + be.x;
        o.y = (v.y - mu[1]) * inv[1] * gm.y + be.y;
        o.z = (v.z - mu[2]) * inv[2] * gm.z + be.z;
        o.w = (v.w - mu[3]) * inv[3] * gm.w + be.w;
        ((float4*)out)[i] = o;
    }
}

extern "C" void kernel_launch(void* const* d_in, const int* in_sizes, int n_in,
                              void* d_out, int out_size, void* d_ws, size_t ws_size,
                              hipStream_t stream) {
    const float* x      = (const float*)d_in[0];
    const float* params = (const float*)d_in[1];
    const float* c1w    = (const float*)d_in[2];
    const float* c1b    = (const float*)d_in[3];
    const float* c2w    = (const float*)d_in[4];
    const float* c2b    = (const float*)d_in[5];
    const float* qkvw   = (const float*)d_in[6];
    const float* qkvb   = (const float*)d_in[7];
    const float* outw   = (const float*)d_in[8];
    const float* outb   = (const float*)d_in[9];
    const float* gamma  = (const float*)d_in[10];
    const float* beta   = (const float*)d_in[11];

    unsigned* w2h = (unsigned*)d_ws;            // 768 uints
    float*    pre = (float*)d_ws + 1024;        // 32768 floats (16B-aligned)

    prep<<<3, 256, 0, stream>>>(c2w, w2h);
    fused_fwd<<<BATCH, 256, 0, stream>>>(x, params, c1w, c1b, c2b,
                                         qkvw, qkvb, outw, outb, w2h, pre);
    bn_final<<<128, 256, 0, stream>>>(pre, gamma, beta, (float*)d_out);
}